// Round 2
// 1747.130 us; speedup vs baseline: 1.2338x; 1.2338x over previous
//
#include <hip/hip_runtime.h>
#include <hip/hip_bf16.h>
#include <stdint.h>

#define HD 512
#define BB 64
#define NSTEP 65          // 1 SOS + 64 teacher-forced tokens
#define MROW 4160         // BB * NSTEP valid output rows
#define MPAD 4224         // 33 * 128 padded rows for GEMM tiling
#define VSZ 32000
#define G3 1536
#define WSTRIDE 520       // padded LDS weight row stride (elements); 1040B = 16B-aligned
#define SPIN_GUARD 65536  // ~10ms; turns a protocol bug into a wrong-answer, not a hang

typedef float f32x4 __attribute__((ext_vector_type(4)));
typedef short bf16x8 __attribute__((ext_vector_type(8)));

__device__ __forceinline__ short f2b(float f) {
  union { float f; uint32_t u; } v; v.f = f;
  uint32_t r = v.u + 0x7FFFu + ((v.u >> 16) & 1u);
  return (short)(r >> 16);
}

__device__ __forceinline__ f32x4 mfma16(bf16x8 a, bf16x8 b, f32x4 c) {
  return __builtin_amdgcn_mfma_f32_16x16x32_bf16(a, b, c, 0, 0, 0);
}

__device__ __forceinline__ float sigm(float x) { return 1.f / (1.f + __expf(-x)); }

__device__ __forceinline__ void gl_lds16(const short* g, short* l) {
  __builtin_amdgcn_global_load_lds((const __attribute__((address_space(1))) void*)g,
                                   (__attribute__((address_space(3))) void*)l, 16, 0, 0);
}

__device__ __forceinline__ void spin_ge(int* f, int need) {
  int guard = 0;
  while (__hip_atomic_load(f, __ATOMIC_RELAXED, __HIP_MEMORY_SCOPE_AGENT) < need &&
         guard < SPIN_GUARD) {
    __builtin_amdgcn_s_sleep(1);
    ++guard;
  }
}

// ---------------- zero scratch (rowsum + flags) ----------------
__global__ void zero_kernel(float* rowsum, int* flags) {
  int i = blockIdx.x * 256 + threadIdx.x;
  if (i < MPAD) rowsum[i] = 0.f;
  if (i < 2048) flags[i] = 0;
}

// ---------------- fp32 -> bf16 weight conversion ----------------
__global__ void convert_kernel(const float* __restrict__ Wfc, const float* __restrict__ Wi0,
                               short* dWfc, short* dWi0) {
  const int wfc4 = VSZ * HD / 4;
  const int tot4 = wfc4 + G3 * HD / 4;
  for (int i = blockIdx.x * 256 + threadIdx.x; i < tot4; i += gridDim.x * 256) {
    const float4* src; short4* dst; int j;
    if (i < wfc4) { src = (const float4*)Wfc; dst = (short4*)dWfc; j = i; }
    else          { src = (const float4*)Wi0; dst = (short4*)dWi0; j = i - wfc4; }
    float4 v = src[j];
    short4 s; s.x = f2b(v.x); s.y = f2b(v.y); s.z = f2b(v.z); s.w = f2b(v.w);
    dst[j] = s;
  }
}

// ---------------- embedding gather -> X bf16, row = t*64 + b ----------------
__global__ void gather_kernel(const float* __restrict__ emb, const int* __restrict__ tgt,
                              short* Xb) {
  const int tot4 = NSTEP * BB * HD / 4;   // 532480
  for (int i = blockIdx.x * 256 + threadIdx.x; i < tot4; i += gridDim.x * 256) {
    int row = i >> 7, q = i & 127;
    int t = row >> 6, b = row & 63;
    int tok = (t == 0) ? 1 : tgt[b * 65 + t - 1];
    float4 v = ((const float4*)(emb + (size_t)tok * HD))[q];
    short4 s; s.x = f2b(v.x); s.y = f2b(v.y); s.z = f2b(v.z); s.w = f2b(v.w);
    ((short4*)Xb)[i] = s;
  }
}

// ---------------- h0 = tanh(cv @ Winit^T + binit) ----------------
// fp32 h0 into h0Af/h0Bf (consumed once into registers by gru_kernel),
// bf16 into history slot 0 of hAh/hBh.
__global__ void __launch_bounds__(256) init_kernel(
    const float* __restrict__ cv, const float* __restrict__ Wi, const float* __restrict__ bi,
    float* h0Af, float* h0Bf, short* hAh, short* hBh) {
  __shared__ float xr[HD];
  const int r = blockIdx.x;  // 0..127: l*64+b
  const int tid = threadIdx.x;
  for (int c = tid; c < HD; c += 256) xr[c] = cv[(size_t)r * HD + c];
  __syncthreads();
  const int b = r & 63;
  float* hf = (r < 64) ? h0Af : h0Bf;
  short* hb = (r < 64) ? hAh : hBh;
  for (int c = tid; c < HD; c += 256) {
    const float4* w4 = (const float4*)(Wi + (size_t)c * HD);
    const float4* x4 = (const float4*)xr;
    float acc = bi[c];
    for (int k = 0; k < HD / 4; ++k) {
      float4 wv = w4[k], xv = x4[k];
      acc += wv.x * xv.x + wv.y * xv.y + wv.z * xv.z + wv.w * xv.w;
    }
    float v = tanhf(acc);
    hf[(size_t)b * HD + c] = v;
    hb[(size_t)b * HD + c] = f2b(v);   // history slot 0
  }
}

// ---------------- generic bf16 GEMM: C[M x N] = A[M x 512] @ Bw[N x 512]^T + bias ----------------
// m97 recipe: 128x128 tile, BK=64, global_load_lds w=16, 16x16x32 MFMA.
__global__ void __launch_bounds__(256) gemm_kernel(
    const short* __restrict__ A, const short* __restrict__ Bw,
    const float* __restrict__ bias, float* __restrict__ C,
    float* rowsum, int N, int mvalid, int do_expsum) {
  __shared__ short sA[128 * 64];
  __shared__ short sB[128 * 64];
  const int tid = threadIdx.x, lane = tid & 63, wv = tid >> 6;
  const size_t m0 = (size_t)blockIdx.y * 128;
  const size_t n0 = (size_t)blockIdx.x * 128;
  const int wm = (wv & 1) * 64, wn = (wv >> 1) * 64;
  f32x4 acc[4][4];
#pragma unroll
  for (int a = 0; a < 4; a++)
#pragma unroll
    for (int b = 0; b < 4; b++) acc[a][b] = (f32x4){0.f, 0.f, 0.f, 0.f};

  for (int k0 = 0; k0 < HD; k0 += 64) {
    __syncthreads();
#pragma unroll
    for (int c = 0; c < 4; ++c) {
      int cc = tid + c * 256;               // 0..1023 chunks of 16B
      int r = cc >> 3, co = (cc & 7) * 8;
      gl_lds16(A + (m0 + r) * HD + k0 + co, sA + cc * 8);
      gl_lds16(Bw + (n0 + r) * HD + k0 + co, sB + cc * 8);
    }
    __syncthreads();
#pragma unroll
    for (int kk = 0; kk < 2; ++kk) {
      const int ko = kk * 32 + (lane >> 4) * 8;
      bf16x8 af[4], bfr[4];
#pragma unroll
      for (int mt = 0; mt < 4; ++mt)
        af[mt] = *(const bf16x8*)(sA + (wm + mt * 16 + (lane & 15)) * 64 + ko);
#pragma unroll
      for (int nt = 0; nt < 4; ++nt)
        bfr[nt] = *(const bf16x8*)(sB + (wn + nt * 16 + (lane & 15)) * 64 + ko);
#pragma unroll
      for (int mt = 0; mt < 4; ++mt)
#pragma unroll
        for (int nt = 0; nt < 4; ++nt)
          acc[mt][nt] = mfma16(af[mt], bfr[nt], acc[mt][nt]);
    }
  }
  const int quad = lane >> 4, cl = lane & 15;
  float bv[4];
#pragma unroll
  for (int nt = 0; nt < 4; ++nt) bv[nt] = bias[n0 + wn + nt * 16 + cl];
#pragma unroll
  for (int mt = 0; mt < 4; ++mt) {
#pragma unroll
    for (int i = 0; i < 4; ++i) {
      size_t row = m0 + wm + mt * 16 + quad * 4 + i;
      if ((int)row >= mvalid) continue;
      float es = 0.f;
#pragma unroll
      for (int nt = 0; nt < 4; ++nt) {
        float v = acc[mt][nt][i] + bv[nt];
        C[row * (size_t)N + n0 + wn + nt * 16 + cl] = v;
        if (do_expsum) es += __expf(v);
      }
      if (do_expsum) {
        es += __shfl_xor(es, 1, 64);
        es += __shfl_xor(es, 2, 64);
        es += __shfl_xor(es, 4, 64);
        es += __shfl_xor(es, 8, 64);
        if (cl == 0) atomicAdd(&rowsum[row], es);
      }
    }
  }
}

// ---------------- persistent GRU recurrence kernel: dataflow flags, no grid barrier ----------------
// 48 WGs x 256 thr. WG 0..15 = layer0 (32 h-cols each, all 64 batch rows),
// WG 16..47 = layer1 (16 h-cols each, both Wi1 & Wh1 slices, all 64 batch rows).
// State: full bf16 history (no WAR hazards), fp32 hidden carried in registers.
// Sync: per-producer monotone flags. Signal = __threadfence + atomicAdd (RMW at the
// coherence point — the exact primitive the proven round-0 grid barrier used).
// Consume = parallel relaxed-agent polls -> barrier -> tid0 acquire fence -> barrier.
__global__ void __launch_bounds__(256) gru_kernel(
    const float* __restrict__ gi0, const float* __restrict__ Wh0,
    const float* __restrict__ Wi1, const float* __restrict__ Wh1,
    const float* __restrict__ bh0, const float* __restrict__ bi1, const float* __restrict__ bh1,
    const float* __restrict__ h0Af, const float* __restrict__ h0Bf,
    short* hAh, short* hBh, short* ysb, int* flags) {
  extern __shared__ char smem[];
  short* wlds = (short*)smem;                       // 96 x WSTRIDE bf16

  const int tid = threadIdx.x;
  const int lane = tid & 63;
  const int wv = tid >> 6;
  const bool g2 = (blockIdx.x >= 16);
  const int w = g2 ? (int)blockIdx.x - 16 : (int)blockIdx.x;

  // --- load bf16 weights into LDS (persistent) ---
  if (!g2) {
    const int j0 = w * 32;
    for (int e = tid; e < 96 * 128; e += 256) {
      int R = e >> 7, q = e & 127;
      int g = R >> 5, jl = R & 31;
      float4 v = ((const float4*)(Wh0 + ((size_t)(g * HD + j0 + jl)) * HD))[q];
      short4 s; s.x = f2b(v.x); s.y = f2b(v.y); s.z = f2b(v.z); s.w = f2b(v.w);
      *(short4*)(wlds + R * WSTRIDE + q * 4) = s;
    }
  } else {
    const int j0 = w * 16;
    for (int e = tid; e < 96 * 128; e += 256) {
      int R = e >> 7, q = e & 127;
      int src = R / 48, rr = R - src * 48;
      int g = rr >> 4, jl = rr & 15;
      const float* W = src ? Wh1 : Wi1;
      float4 v = ((const float4*)(W + ((size_t)(g * HD + j0 + jl)) * HD))[q];
      short4 s; s.x = f2b(v.x); s.y = f2b(v.y); s.z = f2b(v.z); s.w = f2b(v.w);
      *(short4*)(wlds + R * WSTRIDE + q * 4) = s;
    }
  }
  __syncthreads();

  const int quad = lane >> 4;
  const int l15 = lane & 15;
  const int kq = quad * 8;
  const int rbase = wv * 16;            // each wave owns 16 batch rows
  const int arow = rbase + l15;
  int* flagA = flags;                   // 16 producers, stride 32 ints (128B lines)
  int* flagB = flags + 512;             // 32 producers

  if (!g2) {
    // ---------- layer 0 ----------
    const int jb = w * 32;
    float br[2], bz[2], bn[2], hp[4][2];
#pragma unroll
    for (int c = 0; c < 2; ++c) {
      int jg = jb + c * 16 + l15;
      br[c] = bh0[jg]; bz[c] = bh0[HD + jg]; bn[c] = bh0[2 * HD + jg];
    }
#pragma unroll
    for (int i = 0; i < 4; ++i)
#pragma unroll
      for (int c = 0; c < 2; ++c)
        hp[i][c] = h0Af[(size_t)(rbase + quad * 4 + i) * HD + jb + c * 16 + l15];

    for (int p = 0; p < NSTEP; ++p) {
      // prefetch static gi0 for this phase — overlaps the flag spin-wait
      float gv[4][2][3];
#pragma unroll
      for (int i = 0; i < 4; ++i) {
        const float* gi = gi0 + ((size_t)p * BB + rbase + quad * 4 + i) * G3;
#pragma unroll
        for (int c = 0; c < 2; ++c) {
          int jg = jb + c * 16 + l15;
          gv[i][c][0] = gi[jg];
          gv[i][c][1] = gi[HD + jg];
          gv[i][c][2] = gi[2 * HD + jg];
        }
      }
      if (p > 0) {
        if (wv == 0 && lane < 16) spin_ge(&flagA[lane * 32], p);
        __syncthreads();                 // all observations complete
        if (tid == 0) __threadfence();   // acquire: invalidate L1/L2 before reads
        __syncthreads();
      }
      const short* Ab = hAh + (size_t)p * BB * HD + (size_t)arow * HD;
      f32x4 acc[3][2];
#pragma unroll
      for (int g = 0; g < 3; ++g)
#pragma unroll
        for (int c = 0; c < 2; ++c) acc[g][c] = (f32x4){0.f, 0.f, 0.f, 0.f};
#pragma unroll
      for (int ki = 0; ki < 16; ++ki) {
        const int ko = ki * 32 + kq;
        bf16x8 a = *(const bf16x8*)(Ab + ko);
#pragma unroll
        for (int g = 0; g < 3; ++g)
#pragma unroll
          for (int c = 0; c < 2; ++c)
            acc[g][c] = mfma16(a, *(const bf16x8*)(wlds + (g * 32 + c * 16 + l15) * WSTRIDE + ko),
                               acc[g][c]);
      }
      short* Ho = hAh + (size_t)(p + 1) * BB * HD;
#pragma unroll
      for (int i = 0; i < 4; ++i) {
        const int b_ = rbase + quad * 4 + i;
#pragma unroll
        for (int c = 0; c < 2; ++c) {
          const int jg = jb + c * 16 + l15;
          float r = sigm(gv[i][c][0] + acc[0][c][i] + br[c]);
          float z = sigm(gv[i][c][1] + acc[1][c][i] + bz[c]);
          float n = tanhf(gv[i][c][2] + r * (acc[2][c][i] + bn[c]));
          float hv = (1.f - z) * n + z * hp[i][c];
          hp[i][c] = hv;
          Ho[(size_t)b_ * HD + jg] = f2b(hv);
        }
      }
      __syncthreads();                   // drain all threads' stores (vmcnt at barrier)
      if (tid == 0) {
        __threadfence();                 // release: write back to device-visible point
        atomicAdd(&flagA[w * 32], 1);    // RMW signal at coherence point (proven primitive)
      }
    }
  } else {
    // ---------- layer 1 (both GEMMs; EW fully in registers, no exchange) ----------
    const int jb = w * 16;
    const int jg = jb + l15;
    const float brz = bi1[jg] + bh1[jg];
    const float bzz = bi1[HD + jg] + bh1[HD + jg];
    const float bni = bi1[2 * HD + jg];
    const float bnh = bh1[2 * HD + jg];
    float hp[4];
#pragma unroll
    for (int i = 0; i < 4; ++i)
      hp[i] = h0Bf[(size_t)(rbase + quad * 4 + i) * HD + jg];

    for (int t = 0; t < NSTEP; ++t) {
      if (wv == 0 && lane < 48) {
        int* f = (lane < 16) ? &flagA[lane * 32] : &flagB[(lane - 16) * 32];
        const int need = (lane < 16) ? (t + 1) : t;
        spin_ge(f, need);
      }
      __syncthreads();
      if (tid == 0) __threadfence();
      __syncthreads();
      const short* A0 = hAh + (size_t)(t + 1) * BB * HD + (size_t)arow * HD;
      const short* A1 = hBh + (size_t)t * BB * HD + (size_t)arow * HD;
      f32x4 acc[2][3];
#pragma unroll
      for (int s = 0; s < 2; ++s)
#pragma unroll
        for (int g = 0; g < 3; ++g) acc[s][g] = (f32x4){0.f, 0.f, 0.f, 0.f};
#pragma unroll
      for (int ki = 0; ki < 16; ++ki) {
        const int ko = ki * 32 + kq;
        bf16x8 a0 = *(const bf16x8*)(A0 + ko);
        bf16x8 a1 = *(const bf16x8*)(A1 + ko);
#pragma unroll
        for (int g = 0; g < 3; ++g) {
          acc[0][g] = mfma16(a0, *(const bf16x8*)(wlds + (g * 16 + l15) * WSTRIDE + ko), acc[0][g]);
          acc[1][g] = mfma16(a1, *(const bf16x8*)(wlds + (48 + g * 16 + l15) * WSTRIDE + ko), acc[1][g]);
        }
      }
      short* Ho = hBh + (size_t)(t + 1) * BB * HD;
#pragma unroll
      for (int i = 0; i < 4; ++i) {
        const int b_ = rbase + quad * 4 + i;
        float r = sigm(acc[0][0][i] + acc[1][0][i] + brz);
        float z = sigm(acc[0][1][i] + acc[1][1][i] + bzz);
        float n = tanhf(acc[0][2][i] + bni + r * (acc[1][2][i] + bnh));
        float hv = (1.f - z) * n + z * hp[i];
        hp[i] = hv;
        short h16 = f2b(hv);
        Ho[(size_t)b_ * HD + jg] = h16;
        ysb[((size_t)b_ * NSTEP + t) * HD + jg] = h16;   // output row = b*65 + t
      }
      __syncthreads();
      if (tid == 0) {
        __threadfence();
        atomicAdd(&flagB[w * 32], 1);
      }
    }
  }
}

// ---------------- pass 2: out = logits - log(rowsum) in place ----------------
__global__ void logsm_kernel(float* __restrict__ out, const float* __restrict__ rowsum) {
  const unsigned tot4 = (unsigned)MROW * (VSZ / 4);    // 33,280,000
  for (unsigned i = blockIdx.x * 256 + threadIdx.x; i < tot4; i += gridDim.x * 256) {
    unsigned row = i / (VSZ / 4);
    float ls = __logf(rowsum[row]);
    float4 v = ((const float4*)out)[i];
    v.x -= ls; v.y -= ls; v.z -= ls; v.w -= ls;
    ((float4*)out)[i] = v;
  }
}

extern "C" void kernel_launch(void* const* d_in, const int* in_sizes, int n_in,
                              void* d_out, int out_size, void* d_ws, size_t ws_size,
                              hipStream_t stream) {
  (void)in_sizes; (void)n_in; (void)out_size; (void)ws_size;
  const float* cv    = (const float*)d_in[0];
  const int*   tgt   = (const int*)d_in[1];
  const float* emb   = (const float*)d_in[2];
  const float* Winit = (const float*)d_in[3];
  const float* binit = (const float*)d_in[4];
  const float* Wi0   = (const float*)d_in[5];
  const float* Wh0   = (const float*)d_in[6];
  const float* bi0   = (const float*)d_in[7];
  const float* bh0   = (const float*)d_in[8];
  const float* Wi1   = (const float*)d_in[9];
  const float* Wh1   = (const float*)d_in[10];
  const float* bi1   = (const float*)d_in[11];
  const float* bh1   = (const float*)d_in[12];
  const float* Wfc   = (const float*)d_in[13];
  const float* bfc   = (const float*)d_in[14];
  float* out = (float*)d_out;

  char* ws = (char*)d_ws;
  size_t off = 0;
  short* dWfc = (short*)(ws + off); off += (size_t)VSZ * HD * 2;          // 32.77 MB
  short* dWi0 = (short*)(ws + off); off += (size_t)G3 * HD * 2;           // 1.57 MB
  short* Xb   = (short*)(ws + off); off += (size_t)MPAD * HD * 2;         // 4.33 MB
  float* gi0  = (float*)(ws + off); off += (size_t)MPAD * G3 * 4;         // 25.95 MB
  short* ysb  = (short*)(ws + off); off += (size_t)MPAD * HD * 2;         // 4.33 MB
  short* hAh  = (short*)(ws + off); off += (size_t)(NSTEP + 1) * BB * HD * 2;  // 4.33 MB history
  short* hBh  = (short*)(ws + off); off += (size_t)(NSTEP + 1) * BB * HD * 2;  // 4.33 MB history
  float* h0Af = (float*)(ws + off); off += (size_t)BB * HD * 4;
  float* h0Bf = (float*)(ws + off); off += (size_t)BB * HD * 4;
  float* rowsum = (float*)(ws + off); off += (size_t)MPAD * 4;
  int*   flags = (int*)(ws + off); off += 8192;

  zero_kernel<<<17, 256, 0, stream>>>(rowsum, flags);
  convert_kernel<<<2048, 256, 0, stream>>>(Wfc, Wi0, dWfc, dWi0);
  gather_kernel<<<1024, 256, 0, stream>>>(emb, tgt, Xb);
  init_kernel<<<128, 256, 0, stream>>>(cv, Winit, binit, h0Af, h0Bf, hAh, hBh);
  // gi0 = X @ Wi0^T + bi0  (4160 valid rows padded to 4224, N=1536, K=512)
  gemm_kernel<<<dim3(G3 / 128, MPAD / 128), 256, 0, stream>>>(
      Xb, dWi0, bi0, gi0, nullptr, G3, MPAD, 0);

  const size_t smem = (size_t)96 * WSTRIDE * 2;   // 99,840 B
  hipFuncSetAttribute((const void*)gru_kernel,
                      hipFuncAttributeMaxDynamicSharedMemorySize, (int)smem);
  gru_kernel<<<48, 256, smem, stream>>>(gi0, Wh0, Wi1, Wh1, bh0, bi1, bh1,
                                        h0Af, h0Bf, hAh, hBh, ysb, flags);

  // logits = ys @ Wfc^T + bfc into d_out (4160 valid rows), fused exp-rowsum
  gemm_kernel<<<dim3(VSZ / 128, MPAD / 128), 256, 0, stream>>>(
      ysb, dWfc, bfc, out, rowsum, VSZ, MROW, 1);
  logsm_kernel<<<8192, 256, 0, stream>>>(out, rowsum);
}

// Round 3
// 1671.230 us; speedup vs baseline: 1.2898x; 1.0454x over previous
//
#include <hip/hip_runtime.h>
#include <hip/hip_bf16.h>
#include <stdint.h>

#define HD 512
#define BB 64
#define NSTEP 65          // 1 SOS + 64 teacher-forced tokens
#define MROW 4160         // BB * NSTEP valid output rows
#define MPAD 4224         // 33 * 128 padded rows for GEMM tiling
#define VSZ 32000
#define G3 1536
#define WSTRIDE 520       // padded LDS weight row stride (elements); 1040B = 16B-aligned
#define SPIN_GUARD 65536  // ~10ms; turns a protocol bug into a wrong-answer, not a hang

typedef float f32x4 __attribute__((ext_vector_type(4)));
typedef short bf16x8 __attribute__((ext_vector_type(8)));

__device__ __forceinline__ short f2b(float f) {
  union { float f; uint32_t u; } v; v.f = f;
  uint32_t r = v.u + 0x7FFFu + ((v.u >> 16) & 1u);
  return (short)(r >> 16);
}

__device__ __forceinline__ f32x4 mfma16(bf16x8 a, bf16x8 b, f32x4 c) {
  return __builtin_amdgcn_mfma_f32_16x16x32_bf16(a, b, c, 0, 0, 0);
}

__device__ __forceinline__ float sigm(float x) { return 1.f / (1.f + __expf(-x)); }

__device__ __forceinline__ void gl_lds16(const short* g, short* l) {
  __builtin_amdgcn_global_load_lds((const __attribute__((address_space(1))) void*)g,
                                   (__attribute__((address_space(3))) void*)l, 16, 0, 0);
}

__device__ __forceinline__ void spin_ge(int* f, int need) {
  int guard = 0;
  while (__hip_atomic_load(f, __ATOMIC_RELAXED, __HIP_MEMORY_SCOPE_AGENT) < need &&
         guard < SPIN_GUARD) {
    __builtin_amdgcn_s_sleep(1);
    ++guard;
  }
}

// pack own bf16 (at even col l15) with partner lane's bf16 (col l15+1) into one dword,
// store write-through to the coherence point (L3). Even-l15 lanes store; others idle.
__device__ __forceinline__ void coh_store_pair(short* base_col_even, short h16, int l15) {
  unsigned own = (unsigned)(unsigned short)h16;
  unsigned partner = (unsigned)(unsigned short)(short)__shfl_xor((int)h16, 1, 64);
  if ((l15 & 1) == 0) {
    unsigned packed = own | (partner << 16);
    __hip_atomic_store((unsigned*)base_col_even, packed,
                       __ATOMIC_RELAXED, __HIP_MEMORY_SCOPE_AGENT);
  }
}

// ---------------- zero scratch (rowsum + flags) ----------------
__global__ void zero_kernel(float* rowsum, int* flags) {
  int i = blockIdx.x * 256 + threadIdx.x;
  if (i < MPAD) rowsum[i] = 0.f;
  if (i < 2048) flags[i] = 0;
}

// ---------------- fp32 -> bf16 weight conversion ----------------
__global__ void convert_kernel(const float* __restrict__ Wfc, const float* __restrict__ Wi0,
                               short* dWfc, short* dWi0) {
  const int wfc4 = VSZ * HD / 4;
  const int tot4 = wfc4 + G3 * HD / 4;
  for (int i = blockIdx.x * 256 + threadIdx.x; i < tot4; i += gridDim.x * 256) {
    const float4* src; short4* dst; int j;
    if (i < wfc4) { src = (const float4*)Wfc; dst = (short4*)dWfc; j = i; }
    else          { src = (const float4*)Wi0; dst = (short4*)dWi0; j = i - wfc4; }
    float4 v = src[j];
    short4 s; s.x = f2b(v.x); s.y = f2b(v.y); s.z = f2b(v.z); s.w = f2b(v.w);
    dst[j] = s;
  }
}

// ---------------- embedding gather -> X bf16, row = t*64 + b ----------------
__global__ void gather_kernel(const float* __restrict__ emb, const int* __restrict__ tgt,
                              short* Xb) {
  const int tot4 = NSTEP * BB * HD / 4;   // 532480
  for (int i = blockIdx.x * 256 + threadIdx.x; i < tot4; i += gridDim.x * 256) {
    int row = i >> 7, q = i & 127;
    int t = row >> 6, b = row & 63;
    int tok = (t == 0) ? 1 : tgt[b * 65 + t - 1];
    float4 v = ((const float4*)(emb + (size_t)tok * HD))[q];
    short4 s; s.x = f2b(v.x); s.y = f2b(v.y); s.z = f2b(v.z); s.w = f2b(v.w);
    ((short4*)Xb)[i] = s;
  }
}

// ---------------- h0 = tanh(cv @ Winit^T + binit) ----------------
__global__ void __launch_bounds__(256) init_kernel(
    const float* __restrict__ cv, const float* __restrict__ Wi, const float* __restrict__ bi,
    float* h0Af, float* h0Bf, short* hAh, short* hBh) {
  __shared__ float xr[HD];
  const int r = blockIdx.x;  // 0..127: l*64+b
  const int tid = threadIdx.x;
  for (int c = tid; c < HD; c += 256) xr[c] = cv[(size_t)r * HD + c];
  __syncthreads();
  const int b = r & 63;
  float* hf = (r < 64) ? h0Af : h0Bf;
  short* hb = (r < 64) ? hAh : hBh;
  for (int c = tid; c < HD; c += 256) {
    const float4* w4 = (const float4*)(Wi + (size_t)c * HD);
    const float4* x4 = (const float4*)xr;
    float acc = bi[c];
    for (int k = 0; k < HD / 4; ++k) {
      float4 wv = w4[k], xv = x4[k];
      acc += wv.x * xv.x + wv.y * xv.y + wv.z * xv.z + wv.w * xv.w;
    }
    float v = tanhf(acc);
    hf[(size_t)b * HD + c] = v;
    hb[(size_t)b * HD + c] = f2b(v);   // history slot 0 (coherent via kernel boundary)
  }
}

// ---------------- generic bf16 GEMM: C[M x N] = A[M x 512] @ Bw[N x 512]^T + bias ----------------
__global__ void __launch_bounds__(256) gemm_kernel(
    const short* __restrict__ A, const short* __restrict__ Bw,
    const float* __restrict__ bias, float* __restrict__ C,
    float* rowsum, int N, int mvalid, int do_expsum) {
  __shared__ short sA[128 * 64];
  __shared__ short sB[128 * 64];
  const int tid = threadIdx.x, lane = tid & 63, wv = tid >> 6;
  const size_t m0 = (size_t)blockIdx.y * 128;
  const size_t n0 = (size_t)blockIdx.x * 128;
  const int wm = (wv & 1) * 64, wn = (wv >> 1) * 64;
  f32x4 acc[4][4];
#pragma unroll
  for (int a = 0; a < 4; a++)
#pragma unroll
    for (int b = 0; b < 4; b++) acc[a][b] = (f32x4){0.f, 0.f, 0.f, 0.f};

  for (int k0 = 0; k0 < HD; k0 += 64) {
    __syncthreads();
#pragma unroll
    for (int c = 0; c < 4; ++c) {
      int cc = tid + c * 256;               // 0..1023 chunks of 16B
      int r = cc >> 3, co = (cc & 7) * 8;
      gl_lds16(A + (m0 + r) * HD + k0 + co, sA + cc * 8);
      gl_lds16(Bw + (n0 + r) * HD + k0 + co, sB + cc * 8);
    }
    __syncthreads();
#pragma unroll
    for (int kk = 0; kk < 2; ++kk) {
      const int ko = kk * 32 + (lane >> 4) * 8;
      bf16x8 af[4], bfr[4];
#pragma unroll
      for (int mt = 0; mt < 4; ++mt)
        af[mt] = *(const bf16x8*)(sA + (wm + mt * 16 + (lane & 15)) * 64 + ko);
#pragma unroll
      for (int nt = 0; nt < 4; ++nt)
        bfr[nt] = *(const bf16x8*)(sB + (wn + nt * 16 + (lane & 15)) * 64 + ko);
#pragma unroll
      for (int mt = 0; mt < 4; ++mt)
#pragma unroll
        for (int nt = 0; nt < 4; ++nt)
          acc[mt][nt] = mfma16(af[mt], bfr[nt], acc[mt][nt]);
    }
  }
  const int quad = lane >> 4, cl = lane & 15;
  float bv[4];
#pragma unroll
  for (int nt = 0; nt < 4; ++nt) bv[nt] = bias[n0 + wn + nt * 16 + cl];
#pragma unroll
  for (int mt = 0; mt < 4; ++mt) {
#pragma unroll
    for (int i = 0; i < 4; ++i) {
      size_t row = m0 + wm + mt * 16 + quad * 4 + i;
      if ((int)row >= mvalid) continue;
      float es = 0.f;
#pragma unroll
      for (int nt = 0; nt < 4; ++nt) {
        float v = acc[mt][nt][i] + bv[nt];
        C[row * (size_t)N + n0 + wn + nt * 16 + cl] = v;
        if (do_expsum) es += __expf(v);
      }
      if (do_expsum) {
        es += __shfl_xor(es, 1, 64);
        es += __shfl_xor(es, 2, 64);
        es += __shfl_xor(es, 4, 64);
        es += __shfl_xor(es, 8, 64);
        if (cl == 0) atomicAdd(&rowsum[row], es);
      }
    }
  }
}

// ---------------- persistent GRU recurrence kernel: dataflow flags, coherent stores ----------------
// 48 WGs x 256 thr. WG 0..15 = layer0 (32 h-cols each), WG 16..47 = layer1 (16 h-cols each).
// State: full bf16 history; hidden state published with agent-scope relaxed atomic stores
// (write-through to L3 coherence point) -> NO per-step threadfence (no L2 wb/inv).
// Signal = atomicAdd after __syncthreads (vmcnt(0) drains write-through stores to L3).
// Consume = relaxed-agent polls -> __syncthreads -> plain loads (history lines are
// first-touched this dispatch, so no stale L2 copies can exist).
__global__ void __launch_bounds__(256) gru_kernel(
    const float* __restrict__ gi0, const float* __restrict__ Wh0,
    const float* __restrict__ Wi1, const float* __restrict__ Wh1,
    const float* __restrict__ bh0, const float* __restrict__ bi1, const float* __restrict__ bh1,
    const float* __restrict__ h0Af, const float* __restrict__ h0Bf,
    short* hAh, short* hBh, short* ysb, int* flags) {
  extern __shared__ char smem[];
  short* wlds = (short*)smem;                       // 96 x WSTRIDE bf16

  const int tid = threadIdx.x;
  const int lane = tid & 63;
  const int wv = tid >> 6;
  const bool g2 = (blockIdx.x >= 16);
  const int w = g2 ? (int)blockIdx.x - 16 : (int)blockIdx.x;

  // --- load bf16 weights into LDS (persistent) ---
  if (!g2) {
    const int j0 = w * 32;
    for (int e = tid; e < 96 * 128; e += 256) {
      int R = e >> 7, q = e & 127;
      int g = R >> 5, jl = R & 31;
      float4 v = ((const float4*)(Wh0 + ((size_t)(g * HD + j0 + jl)) * HD))[q];
      short4 s; s.x = f2b(v.x); s.y = f2b(v.y); s.z = f2b(v.z); s.w = f2b(v.w);
      *(short4*)(wlds + R * WSTRIDE + q * 4) = s;
    }
  } else {
    const int j0 = w * 16;
    for (int e = tid; e < 96 * 128; e += 256) {
      int R = e >> 7, q = e & 127;
      int src = R / 48, rr = R - src * 48;
      int g = rr >> 4, jl = rr & 15;
      const float* W = src ? Wh1 : Wi1;
      float4 v = ((const float4*)(W + ((size_t)(g * HD + j0 + jl)) * HD))[q];
      short4 s; s.x = f2b(v.x); s.y = f2b(v.y); s.z = f2b(v.z); s.w = f2b(v.w);
      *(short4*)(wlds + R * WSTRIDE + q * 4) = s;
    }
  }
  __syncthreads();

  const int quad = lane >> 4;
  const int l15 = lane & 15;
  const int kq = quad * 8;
  const int rbase = wv * 16;            // each wave owns 16 batch rows
  const int arow = rbase + l15;
  int* flagA = flags;                   // 16 producers, stride 32 ints (128B lines)
  int* flagB = flags + 512;             // 32 producers

  if (!g2) {
    // ---------- layer 0 ----------
    const int jb = w * 32;
    float br[2], bz[2], bn[2], hp[4][2];
#pragma unroll
    for (int c = 0; c < 2; ++c) {
      int jg = jb + c * 16 + l15;
      br[c] = bh0[jg]; bz[c] = bh0[HD + jg]; bn[c] = bh0[2 * HD + jg];
    }
#pragma unroll
    for (int i = 0; i < 4; ++i)
#pragma unroll
      for (int c = 0; c < 2; ++c)
        hp[i][c] = h0Af[(size_t)(rbase + quad * 4 + i) * HD + jb + c * 16 + l15];

    for (int p = 0; p < NSTEP; ++p) {
      // prefetch static gi0 for this phase — overlaps the flag spin-wait
      float gv[4][2][3];
#pragma unroll
      for (int i = 0; i < 4; ++i) {
        const float* gi = gi0 + ((size_t)p * BB + rbase + quad * 4 + i) * G3;
#pragma unroll
        for (int c = 0; c < 2; ++c) {
          int jg = jb + c * 16 + l15;
          gv[i][c][0] = gi[jg];
          gv[i][c][1] = gi[HD + jg];
          gv[i][c][2] = gi[2 * HD + jg];
        }
      }
      if (p > 0) {
        if (wv == 0 && lane < 16) spin_ge(&flagA[lane * 32], p);
        __syncthreads();                 // all observations complete; no fence needed
      }
      const short* Ab = hAh + (size_t)p * BB * HD + (size_t)arow * HD;
      f32x4 acc[3][2];
#pragma unroll
      for (int g = 0; g < 3; ++g)
#pragma unroll
        for (int c = 0; c < 2; ++c) acc[g][c] = (f32x4){0.f, 0.f, 0.f, 0.f};
#pragma unroll
      for (int ki = 0; ki < 16; ++ki) {
        const int ko = ki * 32 + kq;
        bf16x8 a = *(const bf16x8*)(Ab + ko);
#pragma unroll
        for (int g = 0; g < 3; ++g)
#pragma unroll
          for (int c = 0; c < 2; ++c)
            acc[g][c] = mfma16(a, *(const bf16x8*)(wlds + (g * 32 + c * 16 + l15) * WSTRIDE + ko),
                               acc[g][c]);
      }
      short* Ho = hAh + (size_t)(p + 1) * BB * HD;
#pragma unroll
      for (int i = 0; i < 4; ++i) {
        const int b_ = rbase + quad * 4 + i;
#pragma unroll
        for (int c = 0; c < 2; ++c) {
          const int jg = jb + c * 16 + l15;
          float r = sigm(gv[i][c][0] + acc[0][c][i] + br[c]);
          float z = sigm(gv[i][c][1] + acc[1][c][i] + bz[c]);
          float n = tanhf(gv[i][c][2] + r * (acc[2][c][i] + bn[c]));
          float hv = (1.f - z) * n + z * hp[i][c];
          hp[i][c] = hv;
          coh_store_pair(Ho + (size_t)b_ * HD + (jg & ~1), f2b(hv), l15);
        }
      }
      __syncthreads();                   // vmcnt(0): write-through stores acked at L3
      if (tid == 0) atomicAdd(&flagA[w * 32], 1);   // RMW signal at coherence point
    }
  } else {
    // ---------- layer 1 (both GEMMs; EW fully in registers, no exchange) ----------
    const int jb = w * 16;
    const int jg = jb + l15;
    const float brz = bi1[jg] + bh1[jg];
    const float bzz = bi1[HD + jg] + bh1[HD + jg];
    const float bni = bi1[2 * HD + jg];
    const float bnh = bh1[2 * HD + jg];
    float hp[4];
#pragma unroll
    for (int i = 0; i < 4; ++i)
      hp[i] = h0Bf[(size_t)(rbase + quad * 4 + i) * HD + jg];

    for (int t = 0; t < NSTEP; ++t) {
      if (wv == 0 && lane < 48) {
        int* f = (lane < 16) ? &flagA[lane * 32] : &flagB[(lane - 16) * 32];
        const int need = (lane < 16) ? (t + 1) : t;
        spin_ge(f, need);
      }
      __syncthreads();
      const short* A0 = hAh + (size_t)(t + 1) * BB * HD + (size_t)arow * HD;
      const short* A1 = hBh + (size_t)t * BB * HD + (size_t)arow * HD;
      f32x4 acc[2][3];
#pragma unroll
      for (int s = 0; s < 2; ++s)
#pragma unroll
        for (int g = 0; g < 3; ++g) acc[s][g] = (f32x4){0.f, 0.f, 0.f, 0.f};
#pragma unroll
      for (int ki = 0; ki < 16; ++ki) {
        const int ko = ki * 32 + kq;
        bf16x8 a0 = *(const bf16x8*)(A0 + ko);
        bf16x8 a1 = *(const bf16x8*)(A1 + ko);
#pragma unroll
        for (int g = 0; g < 3; ++g) {
          acc[0][g] = mfma16(a0, *(const bf16x8*)(wlds + (g * 16 + l15) * WSTRIDE + ko), acc[0][g]);
          acc[1][g] = mfma16(a1, *(const bf16x8*)(wlds + (48 + g * 16 + l15) * WSTRIDE + ko), acc[1][g]);
        }
      }
      short* Ho = hBh + (size_t)(t + 1) * BB * HD;
#pragma unroll
      for (int i = 0; i < 4; ++i) {
        const int b_ = rbase + quad * 4 + i;
        float r = sigm(acc[0][0][i] + acc[1][0][i] + brz);
        float z = sigm(acc[0][1][i] + acc[1][1][i] + bzz);
        float n = tanhf(acc[0][2][i] + bni + r * (acc[1][2][i] + bnh));
        float hv = (1.f - z) * n + z * hp[i];
        hp[i] = hv;
        short h16 = f2b(hv);
        coh_store_pair(Ho + (size_t)b_ * HD + (jg & ~1), h16, l15);
        ysb[((size_t)b_ * NSTEP + t) * HD + jg] = h16;   // plain: consumed next dispatch
      }
      __syncthreads();
      if (tid == 0) atomicAdd(&flagB[w * 32], 1);
    }
  }
}

// ---------------- pass 2: out = logits - log(rowsum) in place ----------------
__global__ void logsm_kernel(float* __restrict__ out, const float* __restrict__ rowsum) {
  const unsigned tot4 = (unsigned)MROW * (VSZ / 4);    // 33,280,000
  for (unsigned i = blockIdx.x * 256 + threadIdx.x; i < tot4; i += gridDim.x * 256) {
    unsigned row = i / (VSZ / 4);
    float ls = __logf(rowsum[row]);
    float4 v = ((const float4*)out)[i];
    v.x -= ls; v.y -= ls; v.z -= ls; v.w -= ls;
    ((float4*)out)[i] = v;
  }
}

extern "C" void kernel_launch(void* const* d_in, const int* in_sizes, int n_in,
                              void* d_out, int out_size, void* d_ws, size_t ws_size,
                              hipStream_t stream) {
  (void)in_sizes; (void)n_in; (void)out_size; (void)ws_size;
  const float* cv    = (const float*)d_in[0];
  const int*   tgt   = (const int*)d_in[1];
  const float* emb   = (const float*)d_in[2];
  const float* Winit = (const float*)d_in[3];
  const float* binit = (const float*)d_in[4];
  const float* Wi0   = (const float*)d_in[5];
  const float* Wh0   = (const float*)d_in[6];
  const float* bi0   = (const float*)d_in[7];
  const float* bh0   = (const float*)d_in[8];
  const float* Wi1   = (const float*)d_in[9];
  const float* Wh1   = (const float*)d_in[10];
  const float* bi1   = (const float*)d_in[11];
  const float* bh1   = (const float*)d_in[12];
  const float* Wfc   = (const float*)d_in[13];
  const float* bfc   = (const float*)d_in[14];
  float* out = (float*)d_out;

  char* ws = (char*)d_ws;
  size_t off = 0;
  short* dWfc = (short*)(ws + off); off += (size_t)VSZ * HD * 2;          // 32.77 MB
  short* dWi0 = (short*)(ws + off); off += (size_t)G3 * HD * 2;           // 1.57 MB
  short* Xb   = (short*)(ws + off); off += (size_t)MPAD * HD * 2;         // 4.33 MB
  float* gi0  = (float*)(ws + off); off += (size_t)MPAD * G3 * 4;         // 25.95 MB
  short* ysb  = (short*)(ws + off); off += (size_t)MPAD * HD * 2;         // 4.33 MB
  short* hAh  = (short*)(ws + off); off += (size_t)(NSTEP + 1) * BB * HD * 2;  // 4.33 MB history
  short* hBh  = (short*)(ws + off); off += (size_t)(NSTEP + 1) * BB * HD * 2;  // 4.33 MB history
  float* h0Af = (float*)(ws + off); off += (size_t)BB * HD * 4;
  float* h0Bf = (float*)(ws + off); off += (size_t)BB * HD * 4;
  float* rowsum = (float*)(ws + off); off += (size_t)MPAD * 4;
  int*   flags = (int*)(ws + off); off += 8192;

  zero_kernel<<<17, 256, 0, stream>>>(rowsum, flags);
  convert_kernel<<<2048, 256, 0, stream>>>(Wfc, Wi0, dWfc, dWi0);
  gather_kernel<<<1024, 256, 0, stream>>>(emb, tgt, Xb);
  init_kernel<<<128, 256, 0, stream>>>(cv, Winit, binit, h0Af, h0Bf, hAh, hBh);
  // gi0 = X @ Wi0^T + bi0  (4160 valid rows padded to 4224, N=1536, K=512)
  gemm_kernel<<<dim3(G3 / 128, MPAD / 128), 256, 0, stream>>>(
      Xb, dWi0, bi0, gi0, nullptr, G3, MPAD, 0);

  const size_t smem = (size_t)96 * WSTRIDE * 2;   // 99,840 B
  hipFuncSetAttribute((const void*)gru_kernel,
                      hipFuncAttributeMaxDynamicSharedMemorySize, (int)smem);
  gru_kernel<<<48, 256, smem, stream>>>(gi0, Wh0, Wi1, Wh1, bh0, bi1, bh1,
                                        h0Af, h0Bf, hAh, hBh, ysb, flags);

  // logits = ys @ Wfc^T + bfc into d_out (4160 valid rows), fused exp-rowsum
  gemm_kernel<<<dim3(VSZ / 128, MPAD / 128), 256, 0, stream>>>(
      ysb, dWfc, bfc, out, rowsum, VSZ, MROW, 1);
  logsm_kernel<<<8192, 256, 0, stream>>>(out, rowsum);
}

// Round 5
// 1587.234 us; speedup vs baseline: 1.3581x; 1.0529x over previous
//
#include <hip/hip_runtime.h>
#include <hip/hip_bf16.h>
#include <stdint.h>

#define HD 512
#define BB 64
#define NSTEP 65          // 1 SOS + 64 teacher-forced tokens
#define MROW 4160         // BB * NSTEP valid output rows
#define MPAD 4224         // 33 * 128 padded rows for GEMM tiling
#define VSZ 32000
#define G3 1536
#define WSTRIDE 520       // padded LDS weight row stride (elements); 1040B = 16B-aligned
#define SPIN_GUARD 65536  // ~10ms; turns a protocol bug into a wrong-answer, not a hang

typedef float f32x4 __attribute__((ext_vector_type(4)));
typedef short bf16x8 __attribute__((ext_vector_type(8)));

__device__ __forceinline__ short f2b(float f) {
  union { float f; uint32_t u; } v; v.f = f;
  uint32_t r = v.u + 0x7FFFu + ((v.u >> 16) & 1u);
  return (short)(r >> 16);
}

__device__ __forceinline__ f32x4 mfma16(bf16x8 a, bf16x8 b, f32x4 c) {
  return __builtin_amdgcn_mfma_f32_16x16x32_bf16(a, b, c, 0, 0, 0);
}

__device__ __forceinline__ float sigm(float x) { return 1.f / (1.f + __expf(-x)); }

__device__ __forceinline__ void gl_lds16(const short* g, short* l) {
  __builtin_amdgcn_global_load_lds((const __attribute__((address_space(1))) void*)g,
                                   (__attribute__((address_space(3))) void*)l, 16, 0, 0);
}

__device__ __forceinline__ void spin_ge(int* f, int need) {
  int guard = 0;
  while (__hip_atomic_load(f, __ATOMIC_RELAXED, __HIP_MEMORY_SCOPE_AGENT) < need &&
         guard < SPIN_GUARD) {
    __builtin_amdgcn_s_sleep(1);
    ++guard;
  }
}

// pack own bf16 (at even col l15) with partner lane's bf16 (col l15+1) into one dword,
// store write-through to the coherence point (L3). Even-l15 lanes store; others idle.
__device__ __forceinline__ void coh_store_pair(short* base_col_even, short h16, int l15) {
  unsigned own = (unsigned)(unsigned short)h16;
  unsigned partner = (unsigned)(unsigned short)(short)__shfl_xor((int)h16, 1, 64);
  if ((l15 & 1) == 0) {
    unsigned packed = own | (partner << 16);
    __hip_atomic_store((unsigned*)base_col_even, packed,
                       __ATOMIC_RELAXED, __HIP_MEMORY_SCOPE_AGENT);
  }
}

// ---------------- zero scratch (rowsum + flags) ----------------
__global__ void zero_kernel(float* rowsum, int* flags) {
  int i = blockIdx.x * 256 + threadIdx.x;
  if (i < MPAD) rowsum[i] = 0.f;
  if (i < 2048) flags[i] = 0;
}

// ---------------- fp32 -> bf16 weight conversion ----------------
__global__ void convert_kernel(const float* __restrict__ Wfc, const float* __restrict__ Wi0,
                               short* dWfc, short* dWi0) {
  const int wfc4 = VSZ * HD / 4;
  const int tot4 = wfc4 + G3 * HD / 4;
  for (int i = blockIdx.x * 256 + threadIdx.x; i < tot4; i += gridDim.x * 256) {
    const float4* src; short4* dst; int j;
    if (i < wfc4) { src = (const float4*)Wfc; dst = (short4*)dWfc; j = i; }
    else          { src = (const float4*)Wi0; dst = (short4*)dWi0; j = i - wfc4; }
    float4 v = src[j];
    short4 s; s.x = f2b(v.x); s.y = f2b(v.y); s.z = f2b(v.z); s.w = f2b(v.w);
    dst[j] = s;
  }
}

// ---------------- embedding gather -> X bf16, row = t*64 + b ----------------
__global__ void gather_kernel(const float* __restrict__ emb, const int* __restrict__ tgt,
                              short* Xb) {
  const int tot4 = NSTEP * BB * HD / 4;   // 532480
  for (int i = blockIdx.x * 256 + threadIdx.x; i < tot4; i += gridDim.x * 256) {
    int row = i >> 7, q = i & 127;
    int t = row >> 6, b = row & 63;
    int tok = (t == 0) ? 1 : tgt[b * 65 + t - 1];
    float4 v = ((const float4*)(emb + (size_t)tok * HD))[q];
    short4 s; s.x = f2b(v.x); s.y = f2b(v.y); s.z = f2b(v.z); s.w = f2b(v.w);
    ((short4*)Xb)[i] = s;
  }
}

// ---------------- h0 = tanh(cv @ Winit^T + binit) ----------------
__global__ void __launch_bounds__(256) init_kernel(
    const float* __restrict__ cv, const float* __restrict__ Wi, const float* __restrict__ bi,
    float* h0Af, float* h0Bf, short* hAh, short* hBh) {
  __shared__ float xr[HD];
  const int r = blockIdx.x;  // 0..127: l*64+b
  const int tid = threadIdx.x;
  for (int c = tid; c < HD; c += 256) xr[c] = cv[(size_t)r * HD + c];
  __syncthreads();
  const int b = r & 63;
  float* hf = (r < 64) ? h0Af : h0Bf;
  short* hb = (r < 64) ? hAh : hBh;
  for (int c = tid; c < HD; c += 256) {
    const float4* w4 = (const float4*)(Wi + (size_t)c * HD);
    const float4* x4 = (const float4*)xr;
    float acc = bi[c];
    for (int k = 0; k < HD / 4; ++k) {
      float4 wv = w4[k], xv = x4[k];
      acc += wv.x * xv.x + wv.y * xv.y + wv.z * xv.z + wv.w * xv.w;
    }
    float v = tanhf(acc);
    hf[(size_t)b * HD + c] = v;
    hb[(size_t)b * HD + c] = f2b(v);   // history slot 0 (coherent via kernel boundary)
  }
}

// ---------------- generic bf16 GEMM: C[M x N] = A[M x 512] @ Bw[N x 512]^T + bias ----------------
// Flat 1-D grid with chunked m-fastest swizzle: 8 n-tiles interleaved (XCD spread),
// all Mtiles of each n-tile temporally adjacent -> B-tile fetched once, reused 33x from L2/L3.
// do_expsum==1 also selects non-temporal C stores (logits have no reuse before logsm).
__global__ void __launch_bounds__(256) gemm_kernel(
    const short* __restrict__ A, const short* __restrict__ Bw,
    const float* __restrict__ bias, float* __restrict__ C,
    float* rowsum, int N, int mvalid, int do_expsum, int Mtiles, int Ntiles) {
  __shared__ short sA[128 * 64];
  __shared__ short sB[128 * 64];
  const int tid = threadIdx.x, lane = tid & 63, wv = tid >> 6;

  // chunked swizzle: c = chunk of up-to-8 n-tiles; within chunk m runs fastest per n.
  const int PER = 8 * Mtiles;
  const int id = (int)blockIdx.x;
  const int c_ = id / PER;
  const int rem = id - c_ * PER;
  int width = Ntiles - c_ * 8; if (width > 8) width = 8;
  const int tn_ = c_ * 8 + rem % width;
  const int tm_ = rem / width;
  const size_t m0 = (size_t)tm_ * 128;
  const size_t n0 = (size_t)tn_ * 128;

  const int wm = (wv & 1) * 64, wn = (wv >> 1) * 64;
  f32x4 acc[4][4];
#pragma unroll
  for (int a = 0; a < 4; a++)
#pragma unroll
    for (int b = 0; b < 4; b++) acc[a][b] = (f32x4){0.f, 0.f, 0.f, 0.f};

  for (int k0 = 0; k0 < HD; k0 += 64) {
    __syncthreads();
#pragma unroll
    for (int c = 0; c < 4; ++c) {
      int cc = tid + c * 256;               // 0..1023 chunks of 16B
      int r = cc >> 3, co = (cc & 7) * 8;
      gl_lds16(A + (m0 + r) * HD + k0 + co, sA + cc * 8);
      gl_lds16(Bw + (n0 + r) * HD + k0 + co, sB + cc * 8);
    }
    __syncthreads();
#pragma unroll
    for (int kk = 0; kk < 2; ++kk) {
      const int ko = kk * 32 + (lane >> 4) * 8;
      bf16x8 af[4], bfr[4];
#pragma unroll
      for (int mt = 0; mt < 4; ++mt)
        af[mt] = *(const bf16x8*)(sA + (wm + mt * 16 + (lane & 15)) * 64 + ko);
#pragma unroll
      for (int nt = 0; nt < 4; ++nt)
        bfr[nt] = *(const bf16x8*)(sB + (wn + nt * 16 + (lane & 15)) * 64 + ko);
#pragma unroll
      for (int mt = 0; mt < 4; ++mt)
#pragma unroll
        for (int nt = 0; nt < 4; ++nt)
          acc[mt][nt] = mfma16(af[mt], bfr[nt], acc[mt][nt]);
    }
  }
  const int quad = lane >> 4, cl = lane & 15;
  float bv[4];
#pragma unroll
  for (int nt = 0; nt < 4; ++nt) bv[nt] = bias[n0 + wn + nt * 16 + cl];
#pragma unroll
  for (int mt = 0; mt < 4; ++mt) {
#pragma unroll
    for (int i = 0; i < 4; ++i) {
      size_t row = m0 + wm + mt * 16 + quad * 4 + i;
      if ((int)row >= mvalid) continue;
      float es = 0.f;
#pragma unroll
      for (int nt = 0; nt < 4; ++nt) {
        float v = acc[mt][nt][i] + bv[nt];
        float* dst = &C[row * (size_t)N + n0 + wn + nt * 16 + cl];
        if (do_expsum) {
          __builtin_nontemporal_store(v, dst);   // streaming: don't evict B/A from L3
          es += __expf(v);
        } else {
          *dst = v;                               // gi0: keep L3-resident for gru
        }
      }
      if (do_expsum) {
        es += __shfl_xor(es, 1, 64);
        es += __shfl_xor(es, 2, 64);
        es += __shfl_xor(es, 4, 64);
        es += __shfl_xor(es, 8, 64);
        if (cl == 0) atomicAdd(&rowsum[row], es);
      }
    }
  }
}

// ---------------- persistent GRU recurrence kernel: dataflow flags, coherent stores ----------------
// 48 WGs x 256 thr. WG 0..15 = layer0 (32 h-cols each), WG 16..47 = layer1 (16 h-cols each).
// State: full bf16 history; hidden state published with agent-scope relaxed atomic stores
// (write-through to L3 coherence point) -> NO per-step threadfence (no L2 wb/inv).
__global__ void __launch_bounds__(256) gru_kernel(
    const float* __restrict__ gi0, const float* __restrict__ Wh0,
    const float* __restrict__ Wi1, const float* __restrict__ Wh1,
    const float* __restrict__ bh0, const float* __restrict__ bi1, const float* __restrict__ bh1,
    const float* __restrict__ h0Af, const float* __restrict__ h0Bf,
    short* hAh, short* hBh, short* ysb, int* flags) {
  extern __shared__ char smem[];
  short* wlds = (short*)smem;                       // 96 x WSTRIDE bf16

  const int tid = threadIdx.x;
  const int lane = tid & 63;
  const int wv = tid >> 6;
  const bool g2 = (blockIdx.x >= 16);
  const int w = g2 ? (int)blockIdx.x - 16 : (int)blockIdx.x;

  // --- load bf16 weights into LDS (persistent) ---
  if (!g2) {
    const int j0 = w * 32;
    for (int e = tid; e < 96 * 128; e += 256) {
      int R = e >> 7, q = e & 127;
      int g = R >> 5, jl = R & 31;
      float4 v = ((const float4*)(Wh0 + ((size_t)(g * HD + j0 + jl)) * HD))[q];
      short4 s; s.x = f2b(v.x); s.y = f2b(v.y); s.z = f2b(v.z); s.w = f2b(v.w);
      *(short4*)(wlds + R * WSTRIDE + q * 4) = s;
    }
  } else {
    const int j0 = w * 16;
    for (int e = tid; e < 96 * 128; e += 256) {
      int R = e >> 7, q = e & 127;
      int src = R / 48, rr = R - src * 48;
      int g = rr >> 4, jl = rr & 15;
      const float* W = src ? Wh1 : Wi1;
      float4 v = ((const float4*)(W + ((size_t)(g * HD + j0 + jl)) * HD))[q];
      short4 s; s.x = f2b(v.x); s.y = f2b(v.y); s.z = f2b(v.z); s.w = f2b(v.w);
      *(short4*)(wlds + R * WSTRIDE + q * 4) = s;
    }
  }
  __syncthreads();

  const int quad = lane >> 4;
  const int l15 = lane & 15;
  const int kq = quad * 8;
  const int rbase = wv * 16;            // each wave owns 16 batch rows
  const int arow = rbase + l15;
  int* flagA = flags;                   // 16 producers, stride 32 ints (128B lines)
  int* flagB = flags + 512;             // 32 producers

  if (!g2) {
    // ---------- layer 0 ----------
    const int jb = w * 32;
    float br[2], bz[2], bn[2], hp[4][2];
#pragma unroll
    for (int c = 0; c < 2; ++c) {
      int jg = jb + c * 16 + l15;
      br[c] = bh0[jg]; bz[c] = bh0[HD + jg]; bn[c] = bh0[2 * HD + jg];
    }
#pragma unroll
    for (int i = 0; i < 4; ++i)
#pragma unroll
      for (int c = 0; c < 2; ++c)
        hp[i][c] = h0Af[(size_t)(rbase + quad * 4 + i) * HD + jb + c * 16 + l15];

    for (int p = 0; p < NSTEP; ++p) {
      // prefetch static gi0 for this phase — overlaps the flag spin-wait
      float gv[4][2][3];
#pragma unroll
      for (int i = 0; i < 4; ++i) {
        const float* gi = gi0 + ((size_t)p * BB + rbase + quad * 4 + i) * G3;
#pragma unroll
        for (int c = 0; c < 2; ++c) {
          int jg = jb + c * 16 + l15;
          gv[i][c][0] = gi[jg];
          gv[i][c][1] = gi[HD + jg];
          gv[i][c][2] = gi[2 * HD + jg];
        }
      }
      if (p > 0) {
        if (wv == 0 && lane < 16) spin_ge(&flagA[lane * 32], p);
        __syncthreads();                 // all observations complete; no fence needed
      }
      const short* Ab = hAh + (size_t)p * BB * HD + (size_t)arow * HD;
      f32x4 acc[3][2];
#pragma unroll
      for (int g = 0; g < 3; ++g)
#pragma unroll
        for (int c = 0; c < 2; ++c) acc[g][c] = (f32x4){0.f, 0.f, 0.f, 0.f};
#pragma unroll
      for (int ki = 0; ki < 16; ++ki) {
        const int ko = ki * 32 + kq;
        bf16x8 a = *(const bf16x8*)(Ab + ko);
#pragma unroll
        for (int g = 0; g < 3; ++g)
#pragma unroll
          for (int c = 0; c < 2; ++c)
            acc[g][c] = mfma16(a, *(const bf16x8*)(wlds + (g * 32 + c * 16 + l15) * WSTRIDE + ko),
                               acc[g][c]);
      }
      short* Ho = hAh + (size_t)(p + 1) * BB * HD;
#pragma unroll
      for (int i = 0; i < 4; ++i) {
        const int b_ = rbase + quad * 4 + i;
#pragma unroll
        for (int c = 0; c < 2; ++c) {
          const int jg = jb + c * 16 + l15;
          float r = sigm(gv[i][c][0] + acc[0][c][i] + br[c]);
          float z = sigm(gv[i][c][1] + acc[1][c][i] + bz[c]);
          float n = tanhf(gv[i][c][2] + r * (acc[2][c][i] + bn[c]));
          float hv = (1.f - z) * n + z * hp[i][c];
          hp[i][c] = hv;
          coh_store_pair(Ho + (size_t)b_ * HD + (jg & ~1), f2b(hv), l15);
        }
      }
      __syncthreads();                   // vmcnt(0): write-through stores acked at L3
      if (tid == 0) atomicAdd(&flagA[w * 32], 1);   // RMW signal at coherence point
    }
  } else {
    // ---------- layer 1 (both GEMMs; EW fully in registers, no exchange) ----------
    const int jb = w * 16;
    const int jg = jb + l15;
    const float brz = bi1[jg] + bh1[jg];
    const float bzz = bi1[HD + jg] + bh1[HD + jg];
    const float bni = bi1[2 * HD + jg];
    const float bnh = bh1[2 * HD + jg];
    float hp[4];
#pragma unroll
    for (int i = 0; i < 4; ++i)
      hp[i] = h0Bf[(size_t)(rbase + quad * 4 + i) * HD + jg];

    for (int t = 0; t < NSTEP; ++t) {
      if (wv == 0 && lane < 48) {
        int* f = (lane < 16) ? &flagA[lane * 32] : &flagB[(lane - 16) * 32];
        const int need = (lane < 16) ? (t + 1) : t;
        spin_ge(f, need);
      }
      __syncthreads();
      const short* A0 = hAh + (size_t)(t + 1) * BB * HD + (size_t)arow * HD;
      const short* A1 = hBh + (size_t)t * BB * HD + (size_t)arow * HD;
      f32x4 acc[2][3];
#pragma unroll
      for (int s = 0; s < 2; ++s)
#pragma unroll
        for (int g = 0; g < 3; ++g) acc[s][g] = (f32x4){0.f, 0.f, 0.f, 0.f};
#pragma unroll
      for (int ki = 0; ki < 16; ++ki) {
        const int ko = ki * 32 + kq;
        bf16x8 a0 = *(const bf16x8*)(A0 + ko);
        bf16x8 a1 = *(const bf16x8*)(A1 + ko);
#pragma unroll
        for (int g = 0; g < 3; ++g) {
          acc[0][g] = mfma16(a0, *(const bf16x8*)(wlds + (g * 16 + l15) * WSTRIDE + ko), acc[0][g]);
          acc[1][g] = mfma16(a1, *(const bf16x8*)(wlds + (48 + g * 16 + l15) * WSTRIDE + ko), acc[1][g]);
        }
      }
      short* Ho = hBh + (size_t)(t + 1) * BB * HD;
#pragma unroll
      for (int i = 0; i < 4; ++i) {
        const int b_ = rbase + quad * 4 + i;
        float r = sigm(acc[0][0][i] + acc[1][0][i] + brz);
        float z = sigm(acc[0][1][i] + acc[1][1][i] + bzz);
        float n = tanhf(acc[0][2][i] + bni + r * (acc[1][2][i] + bnh));
        float hv = (1.f - z) * n + z * hp[i];
        hp[i] = hv;
        short h16 = f2b(hv);
        coh_store_pair(Ho + (size_t)b_ * HD + (jg & ~1), h16, l15);
        ysb[((size_t)b_ * NSTEP + t) * HD + jg] = h16;   // plain: consumed next dispatch
      }
      __syncthreads();
      if (tid == 0) atomicAdd(&flagB[w * 32], 1);
    }
  }
}

// ---------------- pass 2: out = logits - log(rowsum) in place (streaming) ----------------
__global__ void logsm_kernel(float* __restrict__ out, const float* __restrict__ rowsum) {
  const unsigned tot4 = (unsigned)MROW * (VSZ / 4);    // 33,280,000
  for (unsigned i = blockIdx.x * 256 + threadIdx.x; i < tot4; i += gridDim.x * 256) {
    unsigned row = i / (VSZ / 4);
    float ls = __logf(rowsum[row]);
    f32x4 v = __builtin_nontemporal_load((const f32x4*)out + i);
    v.x -= ls; v.y -= ls; v.z -= ls; v.w -= ls;
    __builtin_nontemporal_store(v, (f32x4*)out + i);
  }
}

extern "C" void kernel_launch(void* const* d_in, const int* in_sizes, int n_in,
                              void* d_out, int out_size, void* d_ws, size_t ws_size,
                              hipStream_t stream) {
  (void)in_sizes; (void)n_in; (void)out_size; (void)ws_size;
  const float* cv    = (const float*)d_in[0];
  const int*   tgt   = (const int*)d_in[1];
  const float* emb   = (const float*)d_in[2];
  const float* Winit = (const float*)d_in[3];
  const float* binit = (const float*)d_in[4];
  const float* Wi0   = (const float*)d_in[5];
  const float* Wh0   = (const float*)d_in[6];
  const float* bi0   = (const float*)d_in[7];
  const float* bh0   = (const float*)d_in[8];
  const float* Wi1   = (const float*)d_in[9];
  const float* Wh1   = (const float*)d_in[10];
  const float* bi1   = (const float*)d_in[11];
  const float* bh1   = (const float*)d_in[12];
  const float* Wfc   = (const float*)d_in[13];
  const float* bfc   = (const float*)d_in[14];
  float* out = (float*)d_out;

  char* ws = (char*)d_ws;
  size_t off = 0;
  short* dWfc = (short*)(ws + off); off += (size_t)VSZ * HD * 2;          // 32.77 MB
  short* dWi0 = (short*)(ws + off); off += (size_t)G3 * HD * 2;           // 1.57 MB
  short* Xb   = (short*)(ws + off); off += (size_t)MPAD * HD * 2;         // 4.33 MB
  float* gi0  = (float*)(ws + off); off += (size_t)MPAD * G3 * 4;         // 25.95 MB
  short* ysb  = (short*)(ws + off); off += (size_t)MPAD * HD * 2;         // 4.33 MB
  short* hAh  = (short*)(ws + off); off += (size_t)(NSTEP + 1) * BB * HD * 2;  // 4.33 MB history
  short* hBh  = (short*)(ws + off); off += (size_t)(NSTEP + 1) * BB * HD * 2;  // 4.33 MB history
  float* h0Af = (float*)(ws + off); off += (size_t)BB * HD * 4;
  float* h0Bf = (float*)(ws + off); off += (size_t)BB * HD * 4;
  float* rowsum = (float*)(ws + off); off += (size_t)MPAD * 4;
  int*   flags = (int*)(ws + off); off += 8192;

  zero_kernel<<<17, 256, 0, stream>>>(rowsum, flags);
  convert_kernel<<<2048, 256, 0, stream>>>(Wfc, Wi0, dWfc, dWi0);
  gather_kernel<<<1024, 256, 0, stream>>>(emb, tgt, Xb);
  init_kernel<<<128, 256, 0, stream>>>(cv, Winit, binit, h0Af, h0Bf, hAh, hBh);
  // gi0 = X @ Wi0^T + bi0  (4160 valid rows padded to 4224, N=1536, K=512)
  gemm_kernel<<<(G3 / 128) * (MPAD / 128), 256, 0, stream>>>(
      Xb, dWi0, bi0, gi0, nullptr, G3, MPAD, 0, MPAD / 128, G3 / 128);

  const size_t smem = (size_t)96 * WSTRIDE * 2;   // 99,840 B
  (void)hipFuncSetAttribute((const void*)gru_kernel,
                            hipFuncAttributeMaxDynamicSharedMemorySize, (int)smem);
  gru_kernel<<<48, 256, smem, stream>>>(gi0, Wh0, Wi1, Wh1, bh0, bi1, bh1,
                                        h0Af, h0Bf, hAh, hBh, ysb, flags);

  // logits = ys @ Wfc^T + bfc into d_out (4160 valid rows), fused exp-rowsum
  gemm_kernel<<<(VSZ / 128) * (MPAD / 128), 256, 0, stream>>>(
      ysb, dWfc, bfc, out, rowsum, VSZ, MROW, 1, MPAD / 128, VSZ / 128);
  logsm_kernel<<<8192, 256, 0, stream>>>(out, rowsum);
}